// Round 11
// baseline (1291.694 us; speedup 1.0000x reference)
//
#include <hip/hip_runtime.h>
#include <math.h>

// VQ-VAE forward. R11: barrier-free, LDS-free MFMA implicit GEMM.
// Activations in zero-padded NHWC (34x34 / 66x66 pitch); B-fragments loaded
// directly from global (padded => unpredicated); relu at producers (dual-write).

typedef unsigned short ushort;
typedef short bf16x8 __attribute__((ext_vector_type(8)));
typedef float f32x4 __attribute__((ext_vector_type(4)));

__device__ __forceinline__ ushort f2bf(float f) {
    unsigned u = __builtin_bit_cast(unsigned, f);
    unsigned r = (u + 0x7fffu + ((u >> 16) & 1u)) >> 16;
    return (ushort)r;
}
__device__ __forceinline__ float bfl(unsigned u) { return __builtin_bit_cast(float, u << 16); }
__device__ __forceinline__ float bfh(unsigned u) { return __builtin_bit_cast(float, u & 0xffff0000u); }

#define P34 1156      // 34*34
#define P66 4356      // 66*66

// ======================= zero borders (B, F: 34-pitch; N64: 66-pitch) ==========
__global__ void k_zerob(ushort* __restrict__ B, ushort* __restrict__ F,
                        ushort* __restrict__ N) {
    long i = (long)blockIdx.x * 256 + threadIdx.x;   // uint4 index
    uint4 z; z.x = z.y = z.z = z.w = 0;
    if (i < 135168) {
        int c = i & 31; long r = i >> 5; int bp = (int)(r % 132); int n = (int)(r / 132);
        int p = bp < 34 ? bp : bp < 68 ? 33 * 34 + (bp - 34)
                : bp < 100 ? (bp - 67) * 34 : (bp - 99) * 34 + 33;
        *(uint4*)(B + ((long)n * P34 + p) * 256 + c * 8) = z;
    } else if (i < 270336) {
        long j = i - 135168;
        int c = j & 31; long r = j >> 5; int bp = (int)(r % 132); int n = (int)(r / 132);
        int p = bp < 34 ? bp : bp < 68 ? 33 * 34 + (bp - 34)
                : bp < 100 ? (bp - 67) * 34 : (bp - 99) * 34 + 33;
        *(uint4*)(F + ((long)n * P34 + p) * 256 + c * 8) = z;
    } else if (i < 536576) {
        long j = i - 270336;
        int c = j & 31; long r = j >> 5; int bp = (int)(r % 260); int n = (int)(r / 260);
        int p = bp < 66 ? bp : bp < 132 ? 65 * 66 + (bp - 66)
                : bp < 196 ? (bp - 131) * 66 : (bp - 195) * 66 + 65;
        *(uint4*)(N + ((long)n * P66 + p) * 256 + c * 8) = z;
    }
}

// ======================= weight packing (unchanged layouts) =====================
__global__ void k_pack_c3x4(const float* __restrict__ w0, const float* __restrict__ w1,
                            const float* __restrict__ w2, const float* __restrict__ w3,
                            ushort* __restrict__ o0, ushort* __restrict__ o1,
                            ushort* __restrict__ o2, ushort* __restrict__ o3) {
    int layer = blockIdx.x / 2304;
    int i = (blockIdx.x - layer * 2304) * 256 + threadIdx.x;
    const float* w = layer == 0 ? w0 : layer == 1 ? w1 : layer == 2 ? w2 : w3;
    ushort* o = layer == 0 ? o0 : layer == 1 ? o1 : layer == 2 ? o2 : o3;
    int kk = i & 31, co = (i >> 5) & 255, cb = (i >> 13) & 7, t = i >> 16;
    int ci = cb * 32 + kk, kh = t / 3, kw = t % 3;
    o[i] = f2bf(w[((co * 256 + ci) * 3 + kh) * 3 + kw]);
}

__global__ void k_pack_c1x1x4(const float* __restrict__ w0, const float* __restrict__ w1,
                              const float* __restrict__ w2, const float* __restrict__ w3,
                              ushort* __restrict__ o0, ushort* __restrict__ o1,
                              ushort* __restrict__ o2, ushort* __restrict__ o3) {
    int layer = blockIdx.x >> 8;
    int i = (blockIdx.x & 255) * 256 + threadIdx.x;
    const float* w = layer == 0 ? w0 : layer == 1 ? w1 : layer == 2 ? w2 : w3;
    ushort* o = layer == 0 ? o0 : layer == 1 ? o1 : layer == 2 ? o2 : o3;
    int kk = i & 31, co = (i >> 5) & 255, cb = (i >> 13) & 7;
    o[i] = f2bf(w[co * 256 + cb * 32 + kk]);
}

__global__ void k_pack_c2dc1(const float* __restrict__ wc2, const float* __restrict__ wdc1,
                             ushort* __restrict__ oc2, ushort* __restrict__ odc1) {
    int g = blockIdx.x;
    int layer = g >> 12;
    int i = (g & 4095) * 256 + threadIdx.x;
    int kk = i & 31, co = (i >> 5) & 255, cb = (i >> 13) & 7;
    int t = (i >> 16) & 3, cls = i >> 18;
    int a = t >> 1, b = t & 1, ci = cb * 32 + kk;
    if (layer == 0) {
        int ph = cls >> 1, pw = cls & 1;
        int kh = ph ? 2 * a : 2 * a + 1;
        int kw = pw ? 2 * b : 2 * b + 1;
        oc2[i] = f2bf(wc2[((co * 256 + ci) * 4 + kh) * 4 + kw]);
    } else {
        int py = cls >> 1, px = cls & 1;
        int kh0 = (py + 1) & 1, kw0 = (px + 1) & 1;
        odc1[i] = f2bf(wdc1[((ci * 256 + co) * 4 + kh0 + 2 * a) * 4 + kw0 + 2 * b]);
    }
}

__global__ void k_pack_c1f(const float* __restrict__ w, float* __restrict__ o) {
    int i = blockIdx.x * 256 + threadIdx.x;
    int co = i & 255, k = i >> 8;
    int ci = k >> 4, kh = (k >> 2) & 3, kw = k & 3;
    o[k * 256 + co] = w[((co * 3 + ci) * 4 + kh) * 4 + kw];
}

__global__ void k_pack_dc2m(const float* __restrict__ w, ushort* __restrict__ o) {
    int i = blockIdx.x * 256 + threadIdx.x;
    int kk = i & 31, oc = (i >> 5) & 15, cb = (i >> 9) & 7, t = i >> 12;
    int dy = t / 3 - 1, dx = t % 3 - 1;
    int ci = cb * 32 + kk;
    float v = 0.f;
    if (oc < 12) {
        int cls = oc / 3, co = oc - cls * 3;
        int py = cls >> 1, px = cls & 1;
        int kh = 1 + py - 2 * dy, kw = 1 + px - 2 * dx;
        if ((unsigned)kh < 4u && (unsigned)kw < 4u)
            v = w[((ci * 3 + co) * 4 + kh) * 4 + kw];
    }
    o[i] = f2bf(v);
}

__global__ void k_pack_vq(const float* __restrict__ cb, ushort* __restrict__ apk,
                          float* __restrict__ en) {
    if (blockIdx.x < 64) {
        int i = blockIdx.x * 256 + threadIdx.x;
        int j = i & 7, lane = (i >> 3) & 63, s = (i >> 9) & 1, t = i >> 10;
        int code = t * 16 + (lane & 15);
        int dim = s * 32 + (lane >> 4) * 8 + j;
        apk[i] = f2bf(cb[code * 64 + dim]);
    } else {
        int code = threadIdx.x;
        float s = 0.f;
        for (int d = 0; d < 64; ++d) { float v = cb[code * 64 + d]; s += v * v; }
        en[code] = s;
    }
}

// ======================= conv1: 3->256 k4 s2, 128->64 -> padded N64 ============
__global__ __launch_bounds__(256) void k_conv1n(const float* __restrict__ x,
                                                const float* __restrict__ wt,
                                                const float* __restrict__ bias,
                                                ushort* __restrict__ o) {
    __shared__ float sx[12][132];
    int b = blockIdx.x;                  // 32n * 64h
    int h = b & 63, n = b >> 6;
    int tid = threadIdx.x;
    for (int c = tid; c < 12 * 128; c += 256) {
        int t = c >> 7, wi = c & 127;
        int ci = t >> 2, kh = t & 3;
        int hi = 2 * h - 1 + kh;
        float v = ((unsigned)hi < 128u) ? x[((long)n * 3 + ci) * 16384 + hi * 128 + wi] : 0.f;
        sx[t][wi + 1] = v;
    }
    if (tid < 24) { int t = tid >> 1; sx[t][(tid & 1) ? 129 : 0] = 0.f; }
    int co = tid;
    float wr[48];
#pragma unroll
    for (int k = 0; k < 48; ++k) wr[k] = wt[k * 256 + co];
    float bco = bias[co];
    __syncthreads();
    ushort* op = o + ((long)n * P66 + (h + 1) * 66 + 1) * 256 + co;
    for (int w = 0; w < 64; ++w) {
        float acc = bco;
#pragma unroll
        for (int t = 0; t < 12; ++t) {
            const float* xr = &sx[t][2 * w];
            acc += xr[0] * wr[t * 4] + xr[1] * wr[t * 4 + 1]
                 + xr[2] * wr[t * 4 + 2] + xr[3] * wr[t * 4 + 3];
        }
        op[w * 256] = f2bf(acc);
    }
}

// ======================= barrier-free MFMA conv =======================
// MODE 0: 3x3 (9 taps), in padded-34   MODE 1: 1x1, in padded-34 interior
// MODE 2: conv2 4x4s2 (4ph x 4taps), in padded-66, out 32x32
// MODE 3: deconv1 per-cls (4 taps), in padded-34, out padded-66 interior
// Block: 256 thr = 4 INDEPENDENT waves (no syncthreads), same co-slab.
// Wave tile 64co x 64m. K-stream software-pipelined with 2-slot reg buffers.
template <int MODE, bool HAS_BIAS, bool ADD_RES, bool WX, bool WXR, bool FLAT>
__global__ __launch_bounds__(256, 2) void k_mconv(const ushort* __restrict__ xin,
                                                  const ushort* __restrict__ wpk,
                                                  const float* __restrict__ bias,
                                                  const ushort* __restrict__ res,
                                                  ushort* __restrict__ ox,
                                                  ushort* __restrict__ oxr) {
    constexpr int NT = (MODE == 0) ? 9 : ((MODE == 1) ? 1 : 4);
    constexpr int NITER = (MODE == 2) ? 32 : 8;
    constexpr int PITCH = (MODE == 2) ? 66 : 34;
    constexpr long NPIX = (MODE == 2) ? P66 : P34;

    int tid = threadIdx.x, lane = tid & 63, wv = tid >> 6;
    int q = lane >> 4, l15 = lane & 15;
    int b = blockIdx.x;
    int mq = b & 3, coslab = (b >> 2) & 3;
    int cls = (MODE == 3) ? ((b >> 4) & 3) : 0;
    int n = (MODE == 3) ? (b >> 6) : (b >> 4);
    int m0 = (mq * 4 + wv) * 64;

    int poff[4];
#pragma unroll
    for (int bt = 0; bt < 4; ++bt) {
        int m = m0 + bt * 16 + l15;
        int h = m >> 5, w = m & 31;
        if (MODE == 2) poff[bt] = ((2 * h + 1) * 66 + (2 * w + 1)) * 256 + q * 8;
        else           poff[bt] = ((h + 1) * 34 + (w + 1)) * 256 + q * 8;
    }
    const ushort* xb = xin + (long)n * NPIX * 256;
    int aoff = (coslab * 64 + l15) * 32 + q * 8;

    f32x4 acc[4][4];
#pragma unroll
    for (int at = 0; at < 4; ++at)
#pragma unroll
        for (int bt = 0; bt < 4; ++bt) acc[at][bt] = 0.f;

    bf16x8 Ab[2][4], Bb[2][4];
    auto load_step = [&](int it, int t, int slot) {
        int cb = (MODE == 2) ? (it >> 2) : it;
        int ph = (MODE == 2) ? (it & 3) : 0;
        int clsi = (MODE == 2) ? ph : ((MODE == 3) ? cls : 0);
        int dy, dx;
        if (MODE == 0) { dy = t / 3 - 1; dx = t % 3 - 1; }
        else if (MODE == 1) { dy = 0; dx = 0; }
        else if (MODE == 2) { dy = 2 * (t >> 1) - (ph >> 1); dx = 2 * (t & 1) - (ph & 1); }
        else { dy = (cls >> 1) - (t >> 1); dx = (cls & 1) - (t & 1); }
        const ushort* bp = xb + cb * 32 + (dy * PITCH + dx) * 256;
#pragma unroll
        for (int bt = 0; bt < 4; ++bt) Bb[slot][bt] = *(const bf16x8*)(bp + poff[bt]);
        const ushort* ap = wpk + ((long)(clsi * NT + t) * 8 + cb) * 8192 + aoff;
#pragma unroll
        for (int at = 0; at < 4; ++at) Ab[slot][at] = *(const bf16x8*)(ap + at * 512);
    };

    load_step(0, 0, 0);
    for (int it2 = 0; it2 < NITER / 2; ++it2) {
#pragma unroll
        for (int tp = 0; tp < 2 * NT; ++tp) {
            int slot = tp & 1, nslot = slot ^ 1;
            // issue next step's loads
            if (tp + 1 < 2 * NT) {
                int nit = it2 * 2 + ((tp + 1) >= NT ? 1 : 0);
                int ntt = ((tp + 1) >= NT) ? (tp + 1 - NT) : (tp + 1);
                load_step(nit, ntt, nslot);
            } else {
                int ni = (it2 + 1 < NITER / 2) ? (it2 + 1) * 2 : 0;
                load_step(ni, 0, nslot);     // wrap-load (harmless) on final step
            }
#pragma unroll
            for (int at = 0; at < 4; ++at)
#pragma unroll
                for (int bt = 0; bt < 4; ++bt)
                    acc[at][bt] = __builtin_amdgcn_mfma_f32_16x16x32_bf16(Ab[slot][at],
                                      Bb[slot][bt], acc[at][bt], 0, 0, 0);
        }
    }

    // ---- epilogue ----
    int co_base = coslab * 64;
#pragma unroll
    for (int at = 0; at < 4; ++at) {
        int co_t = co_base + at * 16 + q * 4;
        float bv[4] = {0.f, 0.f, 0.f, 0.f};
        if (HAS_BIAS) {
            float4 b4 = *(const float4*)(bias + co_t);
            bv[0] = b4.x; bv[1] = b4.y; bv[2] = b4.z; bv[3] = b4.w;
        }
#pragma unroll
        for (int bt = 0; bt < 4; ++bt) {
            int m = m0 + bt * 16 + l15;
            int h = m >> 5, w = m & 31;
            long paddr = ((long)n * P34 + (h + 1) * 34 + (w + 1)) * 256 + co_t;
            long oaddr;
            if (MODE == 3) {
                int py = cls >> 1, px = cls & 1;
                oaddr = ((long)n * P66 + (2 * h + py + 1) * 66 + (2 * w + px + 1)) * 256 + co_t;
            } else if (FLAT) {
                oaddr = ((long)n * 1024 + m) * 256 + co_t;
            } else {
                oaddr = paddr;
            }
            float v[4];
#pragma unroll
            for (int r = 0; r < 4; ++r) v[r] = acc[at][bt][r] + bv[r];
            if (ADD_RES) {
                uint2 rr = *(const uint2*)(res + paddr);
                v[0] += bfl(rr.x); v[1] += bfh(rr.x);
                v[2] += bfl(rr.y); v[3] += bfh(rr.y);
            }
            if (WX) {
                uint2 pk;
                pk.x = (unsigned)f2bf(v[0]) | ((unsigned)f2bf(v[1]) << 16);
                pk.y = (unsigned)f2bf(v[2]) | ((unsigned)f2bf(v[3]) << 16);
                *(uint2*)(ox + oaddr) = pk;
            }
            if (WXR) {
                uint2 pk;
                pk.x = (unsigned)f2bf(fmaxf(v[0], 0.f)) | ((unsigned)f2bf(fmaxf(v[1], 0.f)) << 16);
                pk.y = (unsigned)f2bf(fmaxf(v[2], 0.f)) | ((unsigned)f2bf(fmaxf(v[3], 0.f)) << 16);
                *(uint2*)(oxr + paddr) = pk;
            }
        }
    }
}

// ======================= VQ via MFMA (dual padded writes) ======================
__global__ __launch_bounds__(256) void k_vq2(const ushort* __restrict__ zb,   // flat [row][64]
                                             const ushort* __restrict__ apk,
                                             const float* __restrict__ en,
                                             const float* __restrict__ cbf,
                                             ushort* __restrict__ vqa,        // padded, non-relu
                                             ushort* __restrict__ vqr,        // padded, relu
                                             float* __restrict__ loss) {
    __shared__ int sIdx[64];
    __shared__ float sLoss[64];
    int tid = threadIdx.x, lane = tid & 63, wv = tid >> 6;
    int q = lane >> 4, l15 = lane & 15;
    int r0 = blockIdx.x * 64;
    int R = r0 + wv * 16;

    const ushort* zp = zb + ((long)(R + l15)) * 64 + q * 8;
    bf16x8 b0 = *(const bf16x8*)zp;
    bf16x8 b1 = *(const bf16x8*)(zp + 32);

    float z2 = 0.f;
    {
        const unsigned* u0 = (const unsigned*)&b0;
        const unsigned* u1 = (const unsigned*)&b1;
#pragma unroll
        for (int i = 0; i < 4; ++i) {
            float a = bfl(u0[i]), bb = bfh(u0[i]);
            float c = bfl(u1[i]), d = bfh(u1[i]);
            z2 += a * a + bb * bb + c * c + d * d;
        }
    }

    float best = 3.4e38f;
    int bidx = 0;
#pragma unroll
    for (int t = 0; t < 16; ++t) {
        bf16x8 a0 = *(const bf16x8*)(apk + ((t * 2 + 0) * 64 + lane) * 8);
        bf16x8 a1 = *(const bf16x8*)(apk + ((t * 2 + 1) * 64 + lane) * 8);
        f32x4 acc = {0.f, 0.f, 0.f, 0.f};
        acc = __builtin_amdgcn_mfma_f32_16x16x32_bf16(a0, b0, acc, 0, 0, 0);
        acc = __builtin_amdgcn_mfma_f32_16x16x32_bf16(a1, b1, acc, 0, 0, 0);
        float4 e4 = *(const float4*)(en + t * 16 + q * 4);
        float sc[4] = {e4.x - 2.f * acc[0], e4.y - 2.f * acc[1],
                       e4.z - 2.f * acc[2], e4.w - 2.f * acc[3]};
#pragma unroll
        for (int r = 0; r < 4; ++r) {
            int code = t * 16 + q * 4 + r;
            if (sc[r] < best) { best = sc[r]; bidx = code; }
        }
    }
#pragma unroll
    for (int m = 16; m <= 32; m <<= 1) {
        float ob = __shfl_xor(best, m);
        int oi = __shfl_xor(bidx, m);
        if (ob < best || (ob == best && oi < bidx)) { best = ob; bidx = oi; }
        z2 += __shfl_xor(z2, m);
    }
    if (q == 0) {
        sIdx[wv * 16 + l15] = bidx;
        sLoss[wv * 16 + l15] = best + z2;
    }
    __syncthreads();

    if (wv == 0) {
        float l = sLoss[lane];
#pragma unroll
        for (int m = 1; m < 64; m <<= 1) l += __shfl_xor(l, m);
        if (lane == 0) atomicAdd(loss, l * (1.25f / 8388608.f));
    }

    // block's 16 pixels are contiguous in w (w0 in {0,16})
    int p0 = blockIdx.x * 16;
    int n = p0 >> 10, hp = (p0 & 1023) >> 5, wp0 = p0 & 31;
    long pb = ((long)n * P34 + (hp + 1) * 34 + (wp0 + 1)) * 256;
    unsigned* va = (unsigned*)(vqa + pb);
    unsigned* vr = (unsigned*)(vqr + pb);
#pragma unroll
    for (int k = 0; k < 8; ++k) {
        int i = k * 256 + tid;           // 0..2047 uints = 16px x 128
        int pl = i >> 7, c = i & 127;
        int idx = sIdx[pl * 4 + (c >> 5)];
        int j = c & 31;
        float v0 = cbf[idx * 64 + 2 * j];
        float v1 = cbf[idx * 64 + 2 * j + 1];
        unsigned nr = (unsigned)f2bf(v0) | ((unsigned)f2bf(v1) << 16);
        unsigned rl = (unsigned)f2bf(fmaxf(v0, 0.f)) | ((unsigned)f2bf(fmaxf(v1, 0.f)) << 16);
        long uo = (long)pl * 128 + c;
        va[uo] = nr;
        vr[uo] = rl;
    }
}

// ======================= deconv2 via MFMA (padded-66 input) =====================
#define SDE(r, q, c) (((((r) << 2) + (q)) * 66 + (c)) << 3)

__global__ __launch_bounds__(256, 2) void k_deconv2m(const ushort* __restrict__ xin,
                                                     const ushort* __restrict__ wpk,
                                                     const float* __restrict__ bias,
                                                     float* __restrict__ o) {
    __shared__ __align__(16) ushort sX[6 * 4 * 66 * 8];

    int tid = threadIdx.x, lane = tid & 63, wv = tid >> 6;
    int q = lane >> 4, l15 = lane & 15;
    int b = blockIdx.x;                   // 32n * 16mt
    int mt = b & 15, n = b >> 4;
    int h0 = mt * 4;

    if (tid < 48) {
        int r = tid / 8, rem = tid & 7, qq = rem >> 1, cc = (rem & 1) ? 65 : 0;
        uint4 z; z.x = z.y = z.z = z.w = 0;
        *(uint4*)&sX[SDE(r, qq, cc)] = z;
    }

    int qsel = tid & 3, wst = (tid >> 2) & 63;

    int bbase[4];
#pragma unroll
    for (int bt = 0; bt < 4; ++bt) {
        int mloc = wv * 64 + bt * 16 + l15;
        int ro = mloc >> 6, col = mloc & 63;
        bbase[bt] = SDE(ro + 1, q, col + 1);
    }

    f32x4 acc[4];
#pragma unroll
    for (int bt = 0; bt < 4; ++bt) acc[bt] = 0.f;

    uint4 sreg[6];
    auto stage_load = [&](int cb2) {
#pragma unroll
        for (int r = 0; r < 6; ++r) {
            int hh = h0 + r - 1;   // padded row hh+1 in [0,65]
            sreg[r] = *(const uint4*)(xin + ((long)n * P66 + (hh + 1) * 66 + (wst + 1)) * 256
                                      + cb2 * 32 + qsel * 8);
        }
    };
    stage_load(0);

    for (int cb = 0; cb < 8; ++cb) {
        bf16x8 afA[9];
#pragma unroll
        for (int t = 0; t < 9; ++t)
            afA[t] = *(const bf16x8*)(wpk + (((t * 8 + cb) * 16 + l15) * 32 + q * 8));

        __syncthreads();
#pragma unroll
        for (int r = 0; r < 6; ++r)
            *(uint4*)&sX[SDE(r, qsel, wst + 1)] = sreg[r];
        if (cb < 7) stage_load(cb + 1);
        __syncthreads();

#pragma unroll
        for (int t = 0; t < 9; ++t) {
            int dy = t / 3 - 1, dx = t % 3 - 1;
            int doff = (dy * 4 * 66 + dx) * 8;
#pragma unroll
            for (int bt = 0; bt < 4; ++bt) {
                bf16x8 bf = *(const bf16x8*)&sX[bbase[bt] + doff];
                acc[bt] = __builtin_amdgcn_mfma_f32_16x16x32_bf16(afA[t], bf, acc[bt], 0, 0, 0);
            }
        }
    }

    if (q < 3) {
#pragma unroll
        for (int bt = 0; bt < 4; ++bt) {
            int mloc = wv * 64 + bt * 16 + l15;
            int u = h0 + (mloc >> 6), v = mloc & 63;
#pragma unroll
            for (int r = 0; r < 4; ++r) {
                int oc = q * 4 + r;
                int cls = oc / 3, cs = oc - cls * 3;
                int py = cls >> 1, px = cls & 1;
                o[(((long)n * 3 + cs) * 128 + 2 * u + py) * 128 + 2 * v + px] =
                    tanhf(acc[bt][r] + bias[cs]);
            }
        }
    }
}

// ======================= launcher =======================
extern "C" void kernel_launch(void* const* d_in, const int* in_sizes, int n_in,
                              void* d_out, int out_size, void* d_ws, size_t ws_size,
                              hipStream_t stream) {
    (void)in_sizes; (void)n_in; (void)out_size; (void)ws_size;
    const float* x        = (const float*)d_in[0];
    const float* enc_w1   = (const float*)d_in[1];
    const float* enc_b1   = (const float*)d_in[2];
    const float* enc_w2   = (const float*)d_in[3];
    const float* enc_b2   = (const float*)d_in[4];
    const float* er1_w3   = (const float*)d_in[5];
    const float* er1_w1   = (const float*)d_in[6];
    const float* er2_w3   = (const float*)d_in[7];
    const float* er2_w1   = (const float*)d_in[8];
    const float* codebook = (const float*)d_in[9];
    const float* dr1_w3   = (const float*)d_in[10];
    const float* dr1_w1   = (const float*)d_in[11];
    const float* dr2_w3   = (const float*)d_in[12];
    const float* dr2_w1   = (const float*)d_in[13];
    const float* dt1_w    = (const float*)d_in[14];
    const float* dt1_b    = (const float*)d_in[15];
    const float* dt2_w    = (const float*)d_in[16];
    const float* dt2_b    = (const float*)d_in[17];

    float* recon = (float*)d_out;
    float* loss  = recon + 1572864;

    char* ws = (char*)d_ws;
    size_t off = 0;
    auto alloc = [&](size_t bytes) { char* p = ws + off; off += (bytes + 255) & ~(size_t)255; return p; };
    ushort* N64 = (ushort*)alloc((size_t)32 * P66 * 256 * 2);   // 71.4 MB padded-66
    ushort* A   = (ushort*)alloc((size_t)32 * P34 * 256 * 2);   // 18.9 MB padded-34 each
    ushort* Bp  = (ushort*)alloc((size_t)32 * P34 * 256 * 2);
    ushort* C   = (ushort*)alloc((size_t)32 * P34 * 256 * 2);
    ushort* D   = (ushort*)alloc((size_t)32 * P34 * 256 * 2);
    ushort* F   = (ushort*)alloc((size_t)32 * P34 * 256 * 2);
    ushort* E   = (ushort*)alloc(16777216);                     // flat z for VQ
    ushort* wpk_c2   = (ushort*)alloc(2097152);
    ushort* wpk_dc1  = (ushort*)alloc(2097152);
    ushort* wpk_er13 = (ushort*)alloc(1179648);
    ushort* wpk_er23 = (ushort*)alloc(1179648);
    ushort* wpk_dr13 = (ushort*)alloc(1179648);
    ushort* wpk_dr23 = (ushort*)alloc(1179648);
    ushort* wpk_er11 = (ushort*)alloc(131072);
    ushort* wpk_er21 = (ushort*)alloc(131072);
    ushort* wpk_dr11 = (ushort*)alloc(131072);
    ushort* wpk_dr21 = (ushort*)alloc(131072);
    float*  wt_c1    = (float*)alloc(49152);
    ushort* w2pk     = (ushort*)alloc(73728);
    ushort* apk      = (ushort*)alloc(32768);
    float*  en       = (float*)alloc(1024);

    hipMemsetAsync(loss, 0, sizeof(float), stream);

    // zero borders of tap-read tensors (Bp: relu'd 3x3 inputs; F: deconv1 in; N64)
    k_zerob<<<2096, 256, 0, stream>>>(Bp, F, N64);

    // weight packing
    k_pack_c1f<<<48, 256, 0, stream>>>(enc_w1, wt_c1);
    k_pack_c2dc1<<<8192, 256, 0, stream>>>(enc_w2, dt1_w, wpk_c2, wpk_dc1);
    k_pack_c3x4<<<9216, 256, 0, stream>>>(er1_w3, er2_w3, dr1_w3, dr2_w3,
                                          wpk_er13, wpk_er23, wpk_dr13, wpk_dr23);
    k_pack_c1x1x4<<<1024, 256, 0, stream>>>(er1_w1, er2_w1, dr1_w1, dr2_w1,
                                            wpk_er11, wpk_er21, wpk_dr11, wpk_dr21);
    k_pack_dc2m<<<144, 256, 0, stream>>>(dt2_w, w2pk);
    k_pack_vq<<<65, 256, 0, stream>>>(codebook, apk, en);

    // encoder
    k_conv1n<<<2048, 256, 0, stream>>>(x, wt_c1, enc_b1, N64);
    // conv2: N64 -> A (x, padded) + Bp (relu x, padded)
    k_mconv<2, true, false, true, true, false><<<512, 256, 0, stream>>>(N64, wpk_c2, enc_b2, nullptr, A, Bp);
    // er1: 3x3 Bp -> C (relu'd) ; 1x1 C + res A -> D + Bp(relu)
    k_mconv<0, false, false, false, true, false><<<512, 256, 0, stream>>>(Bp, wpk_er13, nullptr, nullptr, nullptr, C);
    k_mconv<1, false, true, true, true, false><<<512, 256, 0, stream>>>(C, wpk_er11, nullptr, A, D, Bp);
    // er2: 3x3 Bp -> C ; 1x1 C + res D -> E (flat z)
    k_mconv<0, false, false, false, true, false><<<512, 256, 0, stream>>>(Bp, wpk_er23, nullptr, nullptr, nullptr, C);
    k_mconv<1, false, true, true, false, true><<<512, 256, 0, stream>>>(C, wpk_er21, nullptr, D, E, nullptr);
    // VQ: E -> A (vq, padded) + Bp (relu vq, padded) + loss
    k_vq2<<<2048, 256, 0, stream>>>(E, apk, en, codebook, A, Bp, loss);
    // dr1: 3x3 Bp -> C ; 1x1 C + res A -> D + Bp(relu)
    k_mconv<0, false, false, false, true, false><<<512, 256, 0, stream>>>(Bp, wpk_dr13, nullptr, nullptr, nullptr, C);
    k_mconv<1, false, true, true, true, false><<<512, 256, 0, stream>>>(C, wpk_dr11, nullptr, A, D, Bp);
    // dr2: 3x3 Bp -> C ; 1x1 C + res D -> F (padded, non-relu)
    k_mconv<0, false, false, false, true, false><<<512, 256, 0, stream>>>(Bp, wpk_dr23, nullptr, nullptr, nullptr, C);
    k_mconv<1, false, true, true, false, false><<<512, 256, 0, stream>>>(C, wpk_dr21, nullptr, D, F, nullptr);
    // deconv1: F -> N64 interior
    k_mconv<3, true, false, true, false, false><<<2048, 256, 0, stream>>>(F, wpk_dc1, dt1_b, nullptr, N64, nullptr);
    // deconv2 + tanh
    k_deconv2m<<<512, 256, 0, stream>>>(N64, w2pk, dt2_b, recon);
}

// Round 12
// 781.127 us; speedup vs baseline: 1.6536x; 1.6536x over previous
//
#include <hip/hip_runtime.h>
#include <math.h>

// VQ-VAE forward. R12: wave-private double-buffered LDS staging, ZERO barriers
// in all mconv dispatches. Coalesced staging (R10) + barrier-free pipelining.

typedef unsigned short ushort;
typedef short bf16x8 __attribute__((ext_vector_type(8)));
typedef float f32x4 __attribute__((ext_vector_type(4)));

__device__ __forceinline__ ushort f2bf(float f) {
    unsigned u = __builtin_bit_cast(unsigned, f);
    unsigned r = (u + 0x7fffu + ((u >> 16) & 1u)) >> 16;
    return (ushort)r;
}
__device__ __forceinline__ float bfl(unsigned u) { return __builtin_bit_cast(float, u << 16); }
__device__ __forceinline__ float bfh(unsigned u) { return __builtin_bit_cast(float, u & 0xffff0000u); }

__device__ __forceinline__ unsigned relu_u(unsigned u) {
    unsigned m = (u >> 15) & 0x00010001u;
    return u & ~((m << 16) - m);
}
__device__ __forceinline__ uint4 relu4(uint4 v) {
    v.x = relu_u(v.x); v.y = relu_u(v.y); v.z = relu_u(v.z); v.w = relu_u(v.w);
    return v;
}

// ======================= weight packing =======================
// MFMA layout (per layer): [cls][tap][cb(8)][co(256)][k(32)] bf16.

__global__ void k_pack_c3x4(const float* __restrict__ w0, const float* __restrict__ w1,
                            const float* __restrict__ w2, const float* __restrict__ w3,
                            ushort* __restrict__ o0, ushort* __restrict__ o1,
                            ushort* __restrict__ o2, ushort* __restrict__ o3) {
    int layer = blockIdx.x / 2304;
    int i = (blockIdx.x - layer * 2304) * 256 + threadIdx.x;     // 589824
    const float* w = layer == 0 ? w0 : layer == 1 ? w1 : layer == 2 ? w2 : w3;
    ushort* o = layer == 0 ? o0 : layer == 1 ? o1 : layer == 2 ? o2 : o3;
    int kk = i & 31, co = (i >> 5) & 255, cb = (i >> 13) & 7, t = i >> 16;
    int ci = cb * 32 + kk, kh = t / 3, kw = t % 3;
    o[i] = f2bf(w[((co * 256 + ci) * 3 + kh) * 3 + kw]);
}

__global__ void k_pack_c1x1x4(const float* __restrict__ w0, const float* __restrict__ w1,
                              const float* __restrict__ w2, const float* __restrict__ w3,
                              ushort* __restrict__ o0, ushort* __restrict__ o1,
                              ushort* __restrict__ o2, ushort* __restrict__ o3) {
    int layer = blockIdx.x >> 8;
    int i = (blockIdx.x & 255) * 256 + threadIdx.x;              // 65536
    const float* w = layer == 0 ? w0 : layer == 1 ? w1 : layer == 2 ? w2 : w3;
    ushort* o = layer == 0 ? o0 : layer == 1 ? o1 : layer == 2 ? o2 : o3;
    int kk = i & 31, co = (i >> 5) & 255, cb = (i >> 13) & 7;
    o[i] = f2bf(w[co * 256 + cb * 32 + kk]);
}

__global__ void k_pack_c2dc1(const float* __restrict__ wc2, const float* __restrict__ wdc1,
                             ushort* __restrict__ oc2, ushort* __restrict__ odc1) {
    int g = blockIdx.x;
    int layer = g >> 12;
    int i = (g & 4095) * 256 + threadIdx.x;                      // 1048576
    int kk = i & 31, co = (i >> 5) & 255, cb = (i >> 13) & 7;
    int t = (i >> 16) & 3, cls = i >> 18;
    int a = t >> 1, b = t & 1, ci = cb * 32 + kk;
    if (layer == 0) {
        int ph = cls >> 1, pw = cls & 1;
        int kh = ph ? 2 * a : 2 * a + 1;
        int kw = pw ? 2 * b : 2 * b + 1;
        oc2[i] = f2bf(wc2[((co * 256 + ci) * 4 + kh) * 4 + kw]);
    } else {
        int py = cls >> 1, px = cls & 1;
        int kh0 = (py + 1) & 1, kw0 = (px + 1) & 1;
        odc1[i] = f2bf(wdc1[((ci * 256 + co) * 4 + kh0 + 2 * a) * 4 + kw0 + 2 * b]);
    }
}

__global__ void k_pack_c1f(const float* __restrict__ w, float* __restrict__ o) {
    int i = blockIdx.x * 256 + threadIdx.x;           // 12288
    int co = i & 255, k = i >> 8;
    int ci = k >> 4, kh = (k >> 2) & 3, kw = k & 3;
    o[k * 256 + co] = w[((co * 3 + ci) * 4 + kh) * 4 + kw];
}

__global__ void k_pack_dc2m(const float* __restrict__ w, ushort* __restrict__ o) {
    int i = blockIdx.x * 256 + threadIdx.x;           // 36864
    int kk = i & 31, oc = (i >> 5) & 15, cb = (i >> 9) & 7, t = i >> 12;
    int dy = t / 3 - 1, dx = t % 3 - 1;
    int ci = cb * 32 + kk;
    float v = 0.f;
    if (oc < 12) {
        int cls = oc / 3, co = oc - cls * 3;
        int py = cls >> 1, px = cls & 1;
        int kh = 1 + py - 2 * dy, kw = 1 + px - 2 * dx;
        if ((unsigned)kh < 4u && (unsigned)kw < 4u)
            v = w[((ci * 3 + co) * 4 + kh) * 4 + kw];
    }
    o[i] = f2bf(v);
}

__global__ void k_pack_vq(const float* __restrict__ cb, ushort* __restrict__ apk,
                          float* __restrict__ en) {
    if (blockIdx.x < 64) {
        int i = blockIdx.x * 256 + threadIdx.x;
        int j = i & 7, lane = (i >> 3) & 63, s = (i >> 9) & 1, t = i >> 10;
        int code = t * 16 + (lane & 15);
        int dim = s * 32 + (lane >> 4) * 8 + j;
        apk[i] = f2bf(cb[code * 64 + dim]);
    } else {
        int code = threadIdx.x;
        float s = 0.f;
        for (int d = 0; d < 64; ++d) { float v = cb[code * 64 + d]; s += v * v; }
        en[code] = s;
    }
}

// ======================= conv1: 3->256 k4 s2, 128->64, LDS-staged ==============
__global__ __launch_bounds__(256) void k_conv1n(const float* __restrict__ x,
                                                const float* __restrict__ wt,
                                                const float* __restrict__ bias,
                                                ushort* __restrict__ o) {       // NHWC64 bf16
    __shared__ float sx[12][132];
    int b = blockIdx.x;                  // 32n * 64h
    int h = b & 63, n = b >> 6;
    int tid = threadIdx.x;
    for (int c = tid; c < 12 * 128; c += 256) {
        int t = c >> 7, wi = c & 127;
        int ci = t >> 2, kh = t & 3;
        int hi = 2 * h - 1 + kh;
        float v = ((unsigned)hi < 128u) ? x[((long)n * 3 + ci) * 16384 + hi * 128 + wi] : 0.f;
        sx[t][wi + 1] = v;
    }
    if (tid < 24) { int t = tid >> 1; sx[t][(tid & 1) ? 129 : 0] = 0.f; }
    int co = tid;
    float wr[48];
#pragma unroll
    for (int k = 0; k < 48; ++k) wr[k] = wt[k * 256 + co];
    float bco = bias[co];
    __syncthreads();
    ushort* op = o + (((long)n * 64 + h) * 64) * 256 + co;
    for (int w = 0; w < 64; ++w) {
        float acc = bco;
#pragma unroll
        for (int t = 0; t < 12; ++t) {
            const float* xr = &sx[t][2 * w];
            acc += xr[0] * wr[t * 4] + xr[1] * wr[t * 4 + 1]
                 + xr[2] * wr[t * 4 + 2] + xr[3] * wr[t * 4 + 3];
        }
        op[w * 256] = f2bf(acc);
    }
}

// ======================= wave-private barrier-free MFMA conv ====================
// MODE 0: 3x3 (9 taps)  MODE 1: 1x1  MODE 2: conv2 4x4s2 (4ph x 4 taps)
// MODE 3: deconv1 per-cls (4 taps)
// Block: 128 thr = 2 INDEPENDENT waves; wave tile 64co x 64m (2 rows x 32 cols).
// Each wave owns a double-buffered LDS tile: [buf][slot(NR)][q(4)][col(34)][8u].
// NO __syncthreads anywhere; same-wave ds ordering via lgkmcnt.
template <int MODE, bool HAS_BIAS, bool ADD_RES, bool RELU_STAGE, bool RELU_OUT>
__global__ __launch_bounds__(128, 2) void k_mconv(const ushort* __restrict__ xin,
                                                  const ushort* __restrict__ wpk,
                                                  const float* __restrict__ bias,
                                                  const ushort* __restrict__ res,
                                                  ushort* __restrict__ obf) {
    constexpr int NT = (MODE == 0) ? 9 : ((MODE == 1) ? 1 : 4);
    constexpr int NITER = (MODE == 2) ? 32 : 8;
    constexpr int NR = (MODE == 0) ? 4 : ((MODE == 1) ? 2 : 3);
    constexpr int BUFU = NR * 4 * 34 * 8;            // ushorts per buffer
    constexpr int WLDS = 2 * BUFU;                   // per-wave ushorts

    __shared__ __align__(16) ushort sX[2 * WLDS];

    int tid = threadIdx.x, lane = tid & 63, wv = tid >> 6;
    int q = lane >> 4, l15 = lane & 15;
    int b = blockIdx.x;
    int mblk = b & 7, coslab = (b >> 3) & 3;
    int cls = (MODE == 3) ? ((b >> 5) & 3) : 0;
    int n = (MODE == 3) ? (b >> 7) : (b >> 5);
    int R0 = mblk * 4 + wv * 2;                      // wave's first output row

    ushort* sW = sX + wv * WLDS;

    // zero col pads (c=0, c=33) for both buffers, wave-local
    if (lane < 2 * NR * 4 * 2) {
        int cc = (lane & 1) ? 33 : 0;
        int sq = lane >> 1;                          // 0 .. 2*NR*4-1 (spans both bufs)
        uint4 z; z.x = z.y = z.z = z.w = 0;
        *(uint4*)&sW[(sq * 34 + cc) * 8] = z;
    }

    // B-frag pixel decomposition
    int brr[4], bcol[4];
#pragma unroll
    for (int bt = 0; bt < 4; ++bt) {
        int p = bt * 16 + l15;
        brr[bt] = p >> 5; bcol[bt] = (p & 31) + 1;
    }

    // staging lane map: col = lane>>1, two ci-octets j0, j0+1
    int scol = lane >> 1, j0 = (lane & 1) * 2;

    int aoff = (coslab * 64 + l15) * 32 + q * 8;

    f32x4 acc[4][4];
#pragma unroll
    for (int at = 0; at < 4; ++at)
#pragma unroll
        for (int bt = 0; bt < 4; ++bt) acc[at][bt] = 0.f;

    uint4 sreg[NR][2];
    auto stage_load = [&](int it2) {
        int cb2 = (MODE == 2) ? (it2 >> 2) : it2;
        int ph2 = (MODE == 2) ? (it2 & 3) : 0;
        int ph_h2 = ph2 >> 1, ph_w2 = ph2 & 1;
        int hh0 = (MODE == 0) ? R0 - 1 : (MODE == 1) ? R0
                : (MODE == 2) ? R0 - ph_h2 : R0 + (cls >> 1) - 1;
#pragma unroll
        for (int r = 0; r < NR; ++r) {
            int hh = hh0 + r;
            bool valid = (unsigned)hh < 32u;
            long off;
            if (MODE == 2)
                off = (((long)n * 64 + 2 * hh + ph_h2) * 64 + (2 * scol + ph_w2)) * 256 + cb2 * 32 + j0 * 8;
            else
                off = (((long)n * 32 + hh) * 32 + scol) * 256 + cb2 * 32 + j0 * 8;
#pragma unroll
            for (int k = 0; k < 2; ++k) {
                uint4 v;
                if (valid) {
                    v = *(const uint4*)(xin + off + k * 8);
                    if (RELU_STAGE) v = relu4(v);
                } else { v.x = 0; v.y = 0; v.z = 0; v.w = 0; }
                sreg[r][k] = v;
            }
        }
    };
    auto write_stage = [&](int pbuf) {
        ushort* bufp = sW + pbuf * BUFU;
#pragma unroll
        for (int r = 0; r < NR; ++r)
#pragma unroll
            for (int k = 0; k < 2; ++k)
                *(uint4*)&bufp[((r * 4 + j0 + k) * 34 + scol + 1) * 8] = sreg[r][k];
    };

    stage_load(0);
    write_stage(0);

    for (int it = 0; it < NITER; ++it) {
        int cb = (MODE == 2) ? (it >> 2) : it;
        int ph = (MODE == 2) ? (it & 3) : 0;
        int ph_w = ph & 1;
        int clsi = (MODE == 2) ? ph : cls;
        const ushort* wb = wpk + ((long)(clsi * NT) * 8 + cb) * 8192 + aoff;
        ushort* bufp = sW + (it & 1) * BUFU;

        if (it + 1 < NITER) stage_load(it + 1);   // loads in flight during MFMA

        if (MODE == 0) {
            bf16x8 afc[4];
#pragma unroll
            for (int at = 0; at < 4; ++at) afc[at] = *(const bf16x8*)(wb + at * 512);
#pragma unroll
            for (int t = 0; t < 9; ++t) {
                bf16x8 afn[4];
                if (t < 8) {
#pragma unroll
                    for (int at = 0; at < 4; ++at)
                        afn[at] = *(const bf16x8*)(wb + (long)(t + 1) * 65536 + at * 512);
                }
                int taprow = t / 3, dx = t % 3 - 1;
                bf16x8 bfr[4];
#pragma unroll
                for (int bt = 0; bt < 4; ++bt)
                    bfr[bt] = *(const bf16x8*)&bufp[(((brr[bt] + taprow) * 4 + q) * 34 + bcol[bt] + dx) * 8];
#pragma unroll
                for (int at = 0; at < 4; ++at)
#pragma unroll
                    for (int bt = 0; bt < 4; ++bt)
                        acc[at][bt] = __builtin_amdgcn_mfma_f32_16x16x32_bf16(afc[at], bfr[bt],
                                                                              acc[at][bt], 0, 0, 0);
                if (t < 8) {
#pragma unroll
                    for (int at = 0; at < 4; ++at) afc[at] = afn[at];
                }
            }
        } else {
            bf16x8 afA[NT][4];
#pragma unroll
            for (int t = 0; t < NT; ++t)
#pragma unroll
                for (int at = 0; at < 4; ++at)
                    afA[t][at] = *(const bf16x8*)(wb + (long)t * 65536 + at * 512);
#pragma unroll
            for (int t = 0; t < NT; ++t) {
                int taprow, dx;
                if (MODE == 1) { taprow = 0; dx = 0; }
                else if (MODE == 2) { taprow = t >> 1; dx = (t & 1) - ph_w; }
                else { taprow = 1 - (t >> 1); dx = (cls & 1) - (t & 1); }
                bf16x8 bfr[4];
#pragma unroll
                for (int bt = 0; bt < 4; ++bt)
                    bfr[bt] = *(const bf16x8*)&bufp[(((brr[bt] + taprow) * 4 + q) * 34 + bcol[bt] + dx) * 8];
#pragma unroll
                for (int at = 0; at < 4; ++at)
#pragma unroll
                    for (int bt = 0; bt < 4; ++bt)
                        acc[at][bt] = __builtin_amdgcn_mfma_f32_16x16x32_bf16(afA[t][at], bfr[bt],
                                                                              acc[at][bt], 0, 0, 0);
            }
        }

        if (it + 1 < NITER) write_stage((it + 1) & 1);
    }

    // ---- epilogue (all-bf16) ----
    int co_base = coslab * 64;
#pragma unroll
    for (int at = 0; at < 4; ++at) {
        int co_t = co_base + at * 16 + q * 4;
        float bv[4] = {0.f, 0.f, 0.f, 0.f};
        if (HAS_BIAS) {
            float4 b4 = *(const float4*)(bias + co_t);
            bv[0] = b4.x; bv[1] = b4.y; bv[2] = b4.z; bv[3] = b4.w;
        }
#pragma unroll
        for (int bt = 0; bt < 4; ++bt) {
            int m = R0 * 32 + bt * 16 + l15;          // global pixel index
            long oaddr;
            if (MODE == 3) {
                int oy = m >> 5, ox = m & 31;
                int py = cls >> 1, px = cls & 1;
                oaddr = (((long)n * 64 + 2 * oy + py) * 64 + 2 * ox + px) * 256 + co_t;
            } else {
                oaddr = ((long)n * 1024 + m) * 256 + co_t;
            }
            float v[4];
#pragma unroll
            for (int r = 0; r < 4; ++r) v[r] = acc[at][bt][r] + bv[r];
            if (ADD_RES) {
                uint2 rr = *(const uint2*)(res + ((long)n * 1024 + m) * 256 + co_t);
                v[0] += bfl(rr.x); v[1] += bfh(rr.x);
                v[2] += bfl(rr.y); v[3] += bfh(rr.y);
            }
            if (RELU_OUT) {
#pragma unroll
                for (int r = 0; r < 4; ++r) v[r] = fmaxf(v[r], 0.f);
            }
            uint2 pk;
            pk.x = (unsigned)f2bf(v[0]) | ((unsigned)f2bf(v[1]) << 16);
            pk.y = (unsigned)f2bf(v[2]) | ((unsigned)f2bf(v[3]) << 16);
            *(uint2*)(obf + oaddr) = pk;
        }
    }
}

// ======================= VQ via MFMA (bf16 out) =======================
__global__ __launch_bounds__(256) void k_vq2(const ushort* __restrict__ zb,
                                             const ushort* __restrict__ apk,
                                             const float* __restrict__ en,
                                             const float* __restrict__ cbf,
                                             ushort* __restrict__ vqb,
                                             float* __restrict__ loss) {
    __shared__ int sIdx[64];
    __shared__ float sLoss[64];
    int tid = threadIdx.x, lane = tid & 63, wv = tid >> 6;
    int q = lane >> 4, l15 = lane & 15;
    int r0 = blockIdx.x * 64;
    int R = r0 + wv * 16;

    const ushort* zp = zb + ((long)(R + l15)) * 64 + q * 8;
    bf16x8 b0 = *(const bf16x8*)zp;
    bf16x8 b1 = *(const bf16x8*)(zp + 32);

    float z2 = 0.f;
    {
        const unsigned* u0 = (const unsigned*)&b0;
        const unsigned* u1 = (const unsigned*)&b1;
#pragma unroll
        for (int i = 0; i < 4; ++i) {
            float a = bfl(u0[i]), bb = bfh(u0[i]);
            float c = bfl(u1[i]), d = bfh(u1[i]);
            z2 += a * a + bb * bb + c * c + d * d;
        }
    }

    float best = 3.4e38f;
    int bidx = 0;
#pragma unroll
    for (int t = 0; t < 16; ++t) {
        bf16x8 a0 = *(const bf16x8*)(apk + ((t * 2 + 0) * 64 + lane) * 8);
        bf16x8 a1 = *(const bf16x8*)(apk + ((t * 2 + 1) * 64 + lane) * 8);
        f32x4 acc = {0.f, 0.f, 0.f, 0.f};
        acc = __builtin_amdgcn_mfma_f32_16x16x32_bf16(a0, b0, acc, 0, 0, 0);
        acc = __builtin_amdgcn_mfma_f32_16x16x32_bf16(a1, b1, acc, 0, 0, 0);
        float4 e4 = *(const float4*)(en + t * 16 + q * 4);
        float sc[4] = {e4.x - 2.f * acc[0], e4.y - 2.f * acc[1],
                       e4.z - 2.f * acc[2], e4.w - 2.f * acc[3]};
#pragma unroll
        for (int r = 0; r < 4; ++r) {
            int code = t * 16 + q * 4 + r;
            if (sc[r] < best) { best = sc[r]; bidx = code; }
        }
    }
#pragma unroll
    for (int m = 16; m <= 32; m <<= 1) {
        float ob = __shfl_xor(best, m);
        int oi = __shfl_xor(bidx, m);
        if (ob < best || (ob == best && oi < bidx)) { best = ob; bidx = oi; }
        z2 += __shfl_xor(z2, m);
    }
    if (q == 0) {
        sIdx[wv * 16 + l15] = bidx;
        sLoss[wv * 16 + l15] = best + z2;
    }
    __syncthreads();

    if (wv == 0) {
        float l = sLoss[lane];
#pragma unroll
        for (int m = 1; m < 64; m <<= 1) l += __shfl_xor(l, m);
        if (lane == 0) atomicAdd(loss, l * (1.25f / 8388608.f));
    }

    unsigned* vb = (unsigned*)(vqb + (long)r0 * 64);
#pragma unroll
    for (int k = 0; k < 8; ++k) {
        int i = k * 256 + tid;
        int rl = i >> 5, jp = i & 31;
        int idx = sIdx[rl];
        float v0 = cbf[idx * 64 + 2 * jp];
        float v1 = cbf[idx * 64 + 2 * jp + 1];
        vb[i] = (unsigned)f2bf(v0) | ((unsigned)f2bf(v1) << 16);
    }
}

// ======================= deconv2 via MFMA (R10 version) =======================
#define SDE(r, q, c) (((((r) << 2) + (q)) * 66 + (c)) << 3)

__global__ __launch_bounds__(256, 2) void k_deconv2m(const ushort* __restrict__ xin,
                                                     const ushort* __restrict__ wpk,
                                                     const float* __restrict__ bias,
                                                     float* __restrict__ o) {
    __shared__ __align__(16) ushort sX[6 * 4 * 66 * 8];

    int tid = threadIdx.x, lane = tid & 63, wv = tid >> 6;
    int q = lane >> 4, l15 = lane & 15;
    int b = blockIdx.x;                   // 32n * 16mt
    int mt = b & 15, n = b >> 4;
    int h0 = mt * 4;

    if (tid < 48) {
        int r = tid / 8, rem = tid & 7, qq = rem >> 1, cc = (rem & 1) ? 65 : 0;
        uint4 z; z.x = z.y = z.z = z.w = 0;
        *(uint4*)&sX[SDE(r, qq, cc)] = z;
    }

    int qsel = tid & 3, wst = (tid >> 2) & 63;

    int bbase[4];
#pragma unroll
    for (int bt = 0; bt < 4; ++bt) {
        int mloc = wv * 64 + bt * 16 + l15;
        int ro = mloc >> 6, col = mloc & 63;
        bbase[bt] = SDE(ro + 1, q, col + 1);
    }

    f32x4 acc[4];
#pragma unroll
    for (int bt = 0; bt < 4; ++bt) acc[bt] = 0.f;

    uint4 sreg[6];
    auto stage_load = [&](int cb2) {
#pragma unroll
        for (int r = 0; r < 6; ++r) {
            int hh = h0 + r - 1;
            uint4 v;
            if ((unsigned)hh < 64u)
                v = *(const uint4*)(xin + (((long)n * 64 + hh) * 64 + wst) * 256 + cb2 * 32 + qsel * 8);
            else { v.x = 0; v.y = 0; v.z = 0; v.w = 0; }
            sreg[r] = v;
        }
    };
    stage_load(0);

    for (int cb = 0; cb < 8; ++cb) {
        bf16x8 afA[9];
#pragma unroll
        for (int t = 0; t < 9; ++t)
            afA[t] = *(const bf16x8*)(wpk + (((t * 8 + cb) * 16 + l15) * 32 + q * 8));

        __syncthreads();
#pragma unroll
        for (int r = 0; r < 6; ++r)
            *(uint4*)&sX[SDE(r, qsel, wst + 1)] = sreg[r];
        if (cb < 7) stage_load(cb + 1);
        __syncthreads();

#pragma unroll
        for (int t = 0; t < 9; ++t) {
            int dy = t / 3 - 1, dx = t % 3 - 1;
            int doff = (dy * 4 * 66 + dx) * 8;
#pragma unroll
            for (int bt = 0; bt < 4; ++bt) {
                bf16x8 bf = *(const bf16x8*)&sX[bbase[bt] + doff];
                acc[bt] = __builtin_amdgcn_mfma_f32_16x16x32_bf16(afA[t], bf, acc[bt], 0, 0, 0);
            }
        }
    }

    if (q < 3) {
#pragma unroll
        for (int bt = 0; bt < 4; ++bt) {
            int mloc = wv * 64 + bt * 16 + l15;
            int u = h0 + (mloc >> 6), v = mloc & 63;
#pragma unroll
            for (int r = 0; r < 4; ++r) {
                int oc = q * 4 + r;
                int cls = oc / 3, cs = oc - cls * 3;
                int py = cls >> 1, px = cls & 1;
                o[(((long)n * 3 + cs) * 128 + 2 * u + py) * 128 + 2 * v + px] =
                    tanhf(acc[bt][r] + bias[cs]);
            }
        }
    }
}

// ======================= launcher =======================
extern "C" void kernel_launch(void* const* d_in, const int* in_sizes, int n_in,
                              void* d_out, int out_size, void* d_ws, size_t ws_size,
                              hipStream_t stream) {
    (void)in_sizes; (void)n_in; (void)out_size; (void)ws_size;
    const float* x        = (const float*)d_in[0];
    const float* enc_w1   = (const float*)d_in[1];
    const float* enc_b1   = (const float*)d_in[2];
    const float* enc_w2   = (const float*)d_in[3];
    const float* enc_b2   = (const float*)d_in[4];
    const float* er1_w3   = (const float*)d_in[5];
    const float* er1_w1   = (const float*)d_in[6];
    const float* er2_w3   = (const float*)d_in[7];
    const float* er2_w1   = (const float*)d_in[8];
    const float* codebook = (const float*)d_in[9];
    const float* dr1_w3   = (const float*)d_in[10];
    const float* dr1_w1   = (const float*)d_in[11];
    const float* dr2_w3   = (const float*)d_in[12];
    const float* dr2_w1   = (const float*)d_in[13];
    const float* dt1_w    = (const float*)d_in[14];
    const float* dt1_b    = (const float*)d_in[15];
    const float* dt2_w    = (const float*)d_in[16];
    const float* dt2_b    = (const float*)d_in[17];

    float* recon = (float*)d_out;
    float* loss  = recon + 1572864;

    char* ws = (char*)d_ws;
    size_t off = 0;
    auto alloc = [&](size_t bytes) { char* p = ws + off; off += (bytes + 255) & ~(size_t)255; return p; };
    ushort* N64  = (ushort*)alloc(67108864);   // [32,64,64,256] bf16
    ushort* X0   = (ushort*)alloc(16777216);   // bf16 NHWC 32x32 tensors
    ushort* X1   = (ushort*)alloc(16777216);
    ushort* X2   = (ushort*)alloc(16777216);
    ushort* X3   = (ushort*)alloc(16777216);
    ushort* X4   = (ushort*)alloc(16777216);
    ushort* wpk_c2   = (ushort*)alloc(2097152);
    ushort* wpk_dc1  = (ushort*)alloc(2097152);
    ushort* wpk_er13 = (ushort*)alloc(1179648);
    ushort* wpk_er23 = (ushort*)alloc(1179648);
    ushort* wpk_dr13 = (ushort*)alloc(1179648);
    ushort* wpk_dr23 = (ushort*)alloc(1179648);
    ushort* wpk_er11 = (ushort*)alloc(131072);
    ushort* wpk_er21 = (ushort*)alloc(131072);
    ushort* wpk_dr11 = (ushort*)alloc(131072);
    ushort* wpk_dr21 = (ushort*)alloc(131072);
    float*  wt_c1    = (float*)alloc(49152);
    ushort* w2pk     = (ushort*)alloc(73728);
    ushort* apk      = (ushort*)alloc(32768);
    float*  en       = (float*)alloc(1024);

    hipMemsetAsync(loss, 0, sizeof(float), stream);

    // weight packing
    k_pack_c1f<<<48, 256, 0, stream>>>(enc_w1, wt_c1);
    k_pack_c2dc1<<<8192, 256, 0, stream>>>(enc_w2, dt1_w, wpk_c2, wpk_dc1);
    k_pack_c3x4<<<9216, 256, 0, stream>>>(er1_w3, er2_w3, dr1_w3, dr2_w3,
                                          wpk_er13, wpk_er23, wpk_dr13, wpk_dr23);
    k_pack_c1x1x4<<<1024, 256, 0, stream>>>(er1_w1, er2_w1, dr1_w1, dr2_w1,
                                            wpk_er11, wpk_er21, wpk_dr11, wpk_dr21);
    k_pack_dc2m<<<144, 256, 0, stream>>>(dt2_w, w2pk);
    k_pack_vq<<<65, 256, 0, stream>>>(codebook, apk, en);

    // encoder
    k_conv1n<<<2048, 256, 0, stream>>>(x, wt_c1, enc_b1, N64);
    // conv2: N64 -> X0 (z2, no relu)
    k_mconv<2, true, false, false, false><<<1024, 128, 0, stream>>>(N64, wpk_c2, enc_b2, nullptr, X0);
    // er1: 3x3(relu-stage) X0 -> X1(relu'd) ; 1x1 X1 + res X0 -> X2
    k_mconv<0, false, false, true, true><<<1024, 128, 0, stream>>>(X0, wpk_er13, nullptr, nullptr, X1);
    k_mconv<1, false, true, false, false><<<1024, 128, 0, stream>>>(X1, wpk_er11, nullptr, X0, X2);
    // er2: X2 -> X1 ; X1 + res X2 -> X3 (z, VQ input)
    k_mconv<0, false, false, true, true><<<1024, 128, 0, stream>>>(X2, wpk_er23, nullptr, nullptr, X1);
    k_mconv<1, false, true, false, false><<<1024, 128, 0, stream>>>(X1, wpk_er21, nullptr, X2, X3);
    // VQ: X3 -> X4 (vq, no relu) + loss
    k_vq2<<<2048, 256, 0, stream>>>(X3, apk, en, codebook, X4, loss);
    // dr1: X4 -> X1 ; X1 + res X4 -> X0
    k_mconv<0, false, false, true, true><<<1024, 128, 0, stream>>>(X4, wpk_dr13, nullptr, nullptr, X1);
    k_mconv<1, false, true, false, false><<<1024, 128, 0, stream>>>(X1, wpk_dr11, nullptr, X4, X0);
    // dr2: X0 -> X1 ; X1 + res X0 -> X2
    k_mconv<0, false, false, true, true><<<1024, 128, 0, stream>>>(X0, wpk_dr23, nullptr, nullptr, X1);
    k_mconv<1, false, true, false, false><<<1024, 128, 0, stream>>>(X1, wpk_dr21, nullptr, X0, X2);
    // deconv1: X2 -> N64
    k_mconv<3, true, false, false, false><<<4096, 128, 0, stream>>>(X2, wpk_dc1, dt1_b, nullptr, N64);
    // deconv2 + tanh
    k_deconv2m<<<512, 256, 0, stream>>>(N64, w2pk, dt2_b, recon);
}